// Round 3
// baseline (594.410 us; speedup 1.0000x reference)
//
#include <hip/hip_runtime.h>
#include <math.h>

typedef _Float16 f16;
typedef _Float16 f16x8 __attribute__((ext_vector_type(8)));
typedef float f32x4 __attribute__((ext_vector_type(4)));

#define K_HID 2048
#define N_SEQ 4096
#define N_BATCH 2
#define M_ROWS 8192   // B*S

// async global->LDS, 16B per lane. LDS dest must be WAVE-UNIFORM base;
// HW writes lane i at base + i*16 (lane-contiguous, no padding allowed).
__device__ __forceinline__ void gl2lds16(const f16* g, f16* l) {
  auto gp = (const __attribute__((address_space(1))) unsigned*)(unsigned long long)(uintptr_t)g;
  auto lp = (__attribute__((address_space(3))) unsigned*)(unsigned)(uintptr_t)l;
  __builtin_amdgcn_global_load_lds(gp, lp, 16, 0, 0);
}

// ---------------- f32 -> f16 conversion (8 elems/thread) ----------------
__global__ __launch_bounds__(256) void cvt_f32_to_f16(const float* __restrict__ x,
                                                      f16* __restrict__ y, int n) {
  int i = (blockIdx.x * 256 + threadIdx.x) * 8;
  if (i >= n) return;
  float4 a = *(const float4*)(x + i);
  float4 b = *(const float4*)(x + i + 4);
  f16x8 o;
  o[0] = (f16)a.x; o[1] = (f16)a.y; o[2] = (f16)a.z; o[3] = (f16)a.w;
  o[4] = (f16)b.x; o[5] = (f16)b.y; o[6] = (f16)b.z; o[7] = (f16)b.w;
  *(f16x8*)(y + i) = o;
}

// -------- weight transpose+convert: W[K][N] f32 -> Wt[N][K] f16 ----------
__global__ __launch_bounds__(256) void transpose_cvt(const float* __restrict__ W0,
                                                     const float* __restrict__ W1,
                                                     const float* __restrict__ W2,
                                                     const float* __restrict__ W3,
                                                     f16* __restrict__ WT) {
  const float* W = (blockIdx.z == 0) ? W0 : (blockIdx.z == 1) ? W1
                 : (blockIdx.z == 2) ? W2 : W3;
  f16* Wt = WT + (size_t)blockIdx.z * K_HID * K_HID;
  __shared__ float tile[32][33];
  int bx = blockIdx.x * 32;   // n base
  int by = blockIdx.y * 32;   // k base
  int x = threadIdx.x & 31;
  int y = threadIdx.x >> 5;   // 0..7
  for (int i = 0; i < 32; i += 8)
    tile[y + i][x] = W[(size_t)(by + y + i) * K_HID + bx + x];
  __syncthreads();
  for (int i = 0; i < 32; i += 8)
    Wt[(size_t)(bx + y + i) * K_HID + by + x] = (f16)tile[x][y + i];
}

// ---------------- GEMM: C[M][N] = A[M][K] * Bt[N][K]^T ----------------
// 256x256 tile, BK=64, 512 threads = 8 waves (2M x 4N), per-wave 128x64 out.
// 4-phase-per-K-tile schedule (m201-style): phase = (k-half, n-half), each
// {ds_read frags || stage one 16KB (operand,k-half) unit of t+1 || barrier ||
//  lgkmcnt(0) || setprio(1) 16 MFMA setprio(0) || barrier}. K-half split is
// what makes counted vmcnt legal: k1 isn't consumed until phase 2, so
// vmcnt(4) at phases 2 & 3 keeps 4 loads in flight across every barrier
// (never drains to 0, incl. prologue), each unit landing 3-4 phases early.
// LDS [buf][khalf][256][32] f16: 64B row stride makes each wave's b128 frag
// read a contiguous 1024B window -> bank-uniform, NO swizzle needed; staging
// is fully linear (global src and LDS dest).
template <typename OutT>
__global__ __launch_bounds__(512, 2) void gemm_bt(const f16* __restrict__ A,
                                                  const f16* __restrict__ BtBase,
                                                  OutT* __restrict__ CBase,
                                                  int M, int N, int Kd,
                                                  size_t bzStride, size_t czStride) {
  const f16* Bt = BtBase + bzStride * blockIdx.z;
  OutT* C = CBase + czStride * blockIdx.z;
  __shared__ f16 sA[2 * 2 * 256 * 32];   // [buf][kh][row][32k], 32 KiB/buf
  __shared__ f16 sB[2 * 2 * 256 * 32];
  int tid = threadIdx.x;
  int lane = tid & 63, wave = tid >> 6;          // 8 waves
  int quad = lane >> 4, l16 = lane & 15;
  int mBase = blockIdx.y * 256, nBase = blockIdx.x * 256;
  int wm = (wave >> 2) * 128, wn = (wave & 3) * 64;

  f32x4 acc[8][4];
#pragma unroll
  for (int mf = 0; mf < 8; mf++)
#pragma unroll
    for (int nf = 0; nf < 4; nf++) acc[mf][nf] = (f32x4){0.f, 0.f, 0.f, 0.f};

  // staging: one (operand, k-half) unit = 256 rows x 32 k = 16 KB = 2
  // gl2lds/thread. Call j covers rows j*128 + wave*16 + (lane>>2), k-chunk
  // (lane&3)*8 within the half. Linear everywhere (no swizzle).
  int r4 = lane >> 2;            // 0..15
  int kc = (lane & 3) * 8;       // 0,8,16,24
  const f16* Ag = A + (size_t)(mBase + wave * 16 + r4) * Kd + kc;
  const f16* Bg = Bt + (size_t)(nBase + wave * 16 + r4) * Kd + kc;

#define STG(g, dstBase, kh, j, tt)                                           \
  gl2lds16((g) + (size_t)((j) * 128) * Kd + (size_t)((tt) * 64 + (kh) * 32), \
           (dstBase) + (kh) * 8192 + ((j) * 128 + wave * 16) * 32)

  f16* cA = sA;          f16* nA = sA + 16384;
  f16* cB = sB;          f16* nB = sB + 16384;

  const int NT = Kd >> 6;   // 64-wide K-tiles

  // prologue: stage all 4 units of tile 0; drain only the k0 units.
  STG(Ag, cA, 0, 0, 0); STG(Ag, cA, 0, 1, 0);
  STG(Bg, cB, 0, 0, 0); STG(Bg, cB, 0, 1, 0);
  STG(Ag, cA, 1, 0, 0); STG(Ag, cA, 1, 1, 0);
  STG(Bg, cB, 1, 0, 0); STG(Bg, cB, 1, 1, 0);
  asm volatile("s_waitcnt vmcnt(4)" ::: "memory");
  __builtin_amdgcn_s_barrier();

  int aOff = (wm + l16) * 32 + quad * 8;   // + mf*512; +8192 for k-half 1
  int bOff = (wn + l16) * 32 + quad * 8;   // + nf*512

  for (int t = 0; t < NT; ++t) {
    const bool pre = (t + 1 < NT);
    f16x8 af[8], bq[2];
    // ---- phase 0: kh=0, nf 0-1 ----
#pragma unroll
    for (int mf = 0; mf < 8; mf++) af[mf] = *(const f16x8*)&cA[aOff + mf * 512];
#pragma unroll
    for (int nf = 0; nf < 2; nf++) bq[nf] = *(const f16x8*)&cB[bOff + nf * 512];
    if (pre) { STG(Ag, nA, 0, 0, t + 1); STG(Ag, nA, 0, 1, t + 1); }
    __builtin_amdgcn_s_barrier();
    asm volatile("s_waitcnt lgkmcnt(0)" ::: "memory");
    __builtin_amdgcn_sched_barrier(0);
    __builtin_amdgcn_s_setprio(1);
#pragma unroll
    for (int mf = 0; mf < 8; mf++)
#pragma unroll
      for (int nf = 0; nf < 2; nf++)
        acc[mf][nf] = __builtin_amdgcn_mfma_f32_16x16x32_f16(af[mf], bq[nf], acc[mf][nf], 0, 0, 0);
    __builtin_amdgcn_s_setprio(0);
    __builtin_amdgcn_s_barrier();
    // ---- phase 1: kh=0, nf 2-3 ----
#pragma unroll
    for (int nf = 0; nf < 2; nf++) bq[nf] = *(const f16x8*)&cB[bOff + (nf + 2) * 512];
    if (pre) { STG(Bg, nB, 0, 0, t + 1); STG(Bg, nB, 0, 1, t + 1); }
    __builtin_amdgcn_s_barrier();
    asm volatile("s_waitcnt lgkmcnt(0)" ::: "memory");
    __builtin_amdgcn_sched_barrier(0);
    __builtin_amdgcn_s_setprio(1);
#pragma unroll
    for (int mf = 0; mf < 8; mf++)
#pragma unroll
      for (int nf = 0; nf < 2; nf++)
        acc[mf][nf + 2] = __builtin_amdgcn_mfma_f32_16x16x32_f16(af[mf], bq[nf], acc[mf][nf + 2], 0, 0, 0);
    __builtin_amdgcn_s_setprio(0);
    __builtin_amdgcn_s_barrier();
    // ---- phase 2: kh=1, nf 2-3 ----
    // drain A-k1,B-k1 of tile t (oldest 4); leave t+1's k0 units in flight.
    if (pre) asm volatile("s_waitcnt vmcnt(4)" ::: "memory");
    else     asm volatile("s_waitcnt vmcnt(0)" ::: "memory");
#pragma unroll
    for (int mf = 0; mf < 8; mf++) af[mf] = *(const f16x8*)&cA[8192 + aOff + mf * 512];
#pragma unroll
    for (int nf = 0; nf < 2; nf++) bq[nf] = *(const f16x8*)&cB[8192 + bOff + (nf + 2) * 512];
    if (pre) { STG(Ag, nA, 1, 0, t + 1); STG(Ag, nA, 1, 1, t + 1); }
    __builtin_amdgcn_s_barrier();
    asm volatile("s_waitcnt lgkmcnt(0)" ::: "memory");
    __builtin_amdgcn_sched_barrier(0);
    __builtin_amdgcn_s_setprio(1);
#pragma unroll
    for (int mf = 0; mf < 8; mf++)
#pragma unroll
      for (int nf = 0; nf < 2; nf++)
        acc[mf][nf + 2] = __builtin_amdgcn_mfma_f32_16x16x32_f16(af[mf], bq[nf], acc[mf][nf + 2], 0, 0, 0);
    __builtin_amdgcn_s_setprio(0);
    __builtin_amdgcn_s_barrier();
    // ---- phase 3: kh=1, nf 0-1 ----
#pragma unroll
    for (int nf = 0; nf < 2; nf++) bq[nf] = *(const f16x8*)&cB[8192 + bOff + nf * 512];
    if (pre) { STG(Bg, nB, 1, 0, t + 1); STG(Bg, nB, 1, 1, t + 1); }
    // drain t+1's k0 units (oldest 4) before the boundary barrier; k1 floats.
    if (pre) asm volatile("s_waitcnt vmcnt(4)" ::: "memory");
    else     asm volatile("s_waitcnt vmcnt(0)" ::: "memory");
    __builtin_amdgcn_s_barrier();
    asm volatile("s_waitcnt lgkmcnt(0)" ::: "memory");
    __builtin_amdgcn_sched_barrier(0);
    __builtin_amdgcn_s_setprio(1);
#pragma unroll
    for (int mf = 0; mf < 8; mf++)
#pragma unroll
      for (int nf = 0; nf < 2; nf++)
        acc[mf][nf] = __builtin_amdgcn_mfma_f32_16x16x32_f16(af[mf], bq[nf], acc[mf][nf], 0, 0, 0);
    __builtin_amdgcn_s_setprio(0);
    __builtin_amdgcn_s_barrier();
    // swap double buffers
    f16* tA = cA; cA = nA; nA = tA;
    f16* tB = cB; cB = nB; nB = tB;
  }
#undef STG

#pragma unroll
  for (int mf = 0; mf < 8; mf++) {
    int row = mBase + wm + mf * 16 + quad * 4;
#pragma unroll
    for (int nf = 0; nf < 4; nf++) {
      int col = nBase + wn + nf * 16 + l16;
      OutT* Cp = C + (size_t)row * N + col;
#pragma unroll
      for (int r = 0; r < 4; r++) Cp[(size_t)r * N] = (OutT)acc[mf][nf][r];
    }
  }
}

// ---------------- sliding-tile flash attention ----------------
// grid (T=32 tiles, NH=32, B=2), 256 threads. Q tile [128 x 64] resident.
// 8 chunks of 64 keys (4 window tiles x 2 halves), online softmax (base-2).
// sVt uses XOR block-swizzle col' = col ^ (row & 56): breaks the 8-way
// same-bank conflict of transpose writes while keeping b128 fragment reads.
__global__ __launch_bounds__(256) void attn_kernel(const f16* __restrict__ Q,
                                                   const f16* __restrict__ Kg,
                                                   const f16* __restrict__ V,
                                                   f16* __restrict__ O) {
  __shared__ f16 sQ[128 * 72];
  __shared__ f16 sK[64 * 72];
  __shared__ f16 sVt[64 * 72];   // V transposed: [d][key ^ (d&56)]
  __shared__ f16 sP[128 * 72];   // P staged for A-operand layout

  int t = blockIdx.x, h = blockIdx.y, b = blockIdx.z;
  int nth_i = t >> 2, ntw_i = t & 3;    // Ht=8, Wt=4
  int tid = threadIdx.x;
  int lane = tid & 63, wave = tid >> 6;
  int quad = lane >> 4, l16 = lane & 15;
  const size_t bstride = (size_t)N_SEQ * K_HID;
  const f16* Qb = Q + (size_t)b * bstride + h * 64;
  const f16* Kb = Kg + (size_t)b * bstride + h * 64;
  const f16* Vb = V + (size_t)b * bstride + h * 64;

  const float SC2 = 0.18033688f;   // (1/sqrt(64)) * log2(e)

  // load Q tile: row qr -> token s = (nth*8 + qr/16)*64 + ntw*16 + qr%16
  for (int i = tid; i < 1024; i += 256) {
    int qr = i >> 3, dc = (i & 7) * 8;
    int s = (nth_i * 8 + (qr >> 4)) * 64 + ntw_i * 16 + (qr & 15);
    *(float4*)&sQ[qr * 72 + dc] = *(const float4*)&Qb[(size_t)s * K_HID + dc];
  }
  __syncthreads();

  f16x8 qf[2][2];   // [q-subtile][k-step], resident for all chunks
#pragma unroll
  for (int qs = 0; qs < 2; qs++)
#pragma unroll
    for (int kk = 0; kk < 2; kk++)
      qf[qs][kk] = *(const f16x8*)&sQ[(wave * 32 + qs * 16 + l16) * 72 + kk * 32 + quad * 8];

  f32x4 oacc[2][4];
#pragma unroll
  for (int qs = 0; qs < 2; qs++)
#pragma unroll
    for (int dt = 0; dt < 4; dt++) oacc[qs][dt] = (f32x4){0.f, 0.f, 0.f, 0.f};
  float mrow[2][4], lrow[2][4];
#pragma unroll
  for (int qs = 0; qs < 2; qs++)
#pragma unroll
    for (int r = 0; r < 4; r++) { mrow[qs][r] = -1e30f; lrow[qs][r] = 0.f; }

  int cr = min(max(nth_i, 1), 7);   // clamped window center (tile units)
  int cc = min(max(ntw_i, 1), 3);

  for (int c = 0; c < 8; c++) {
    int kt = c >> 1, half = c & 1;
    int ti = cr - 1 + (kt >> 1), tj = cc - 1 + (kt & 1);
    // stage K chunk [64 x 64] and swizzled V^T chunk
    for (int i = tid; i < 512; i += 256) {
      int kl = i >> 3, dc = (i & 7) * 8;
      int kr = half * 64 + kl;
      int s = (ti * 8 + (kr >> 4)) * 64 + tj * 16 + (kr & 15);
      *(float4*)&sK[kl * 72 + dc] = *(const float4*)&Kb[(size_t)s * K_HID + dc];
      f16x8 vv = *(const f16x8*)&Vb[(size_t)s * K_HID + dc];
      int sw = kl ^ dc;   // dc == (row & 56) for rows dc..dc+7
#pragma unroll
      for (int j = 0; j < 8; j++) sVt[(dc + j) * 72 + sw] = vv[j];
    }
    __syncthreads();

    // S = Q K^T (raw logits; scale folded into base-2 softmax)
    f32x4 sacc[2][4];
#pragma unroll
    for (int qs = 0; qs < 2; qs++)
#pragma unroll
      for (int ks = 0; ks < 4; ks++) sacc[qs][ks] = (f32x4){0.f, 0.f, 0.f, 0.f};
#pragma unroll
    for (int ks = 0; ks < 4; ks++) {
      f16x8 kf0 = *(const f16x8*)&sK[(ks * 16 + l16) * 72 + quad * 8];
      f16x8 kf1 = *(const f16x8*)&sK[(ks * 16 + l16) * 72 + 32 + quad * 8];
#pragma unroll
      for (int qs = 0; qs < 2; qs++) {
        sacc[qs][ks] = __builtin_amdgcn_mfma_f32_16x16x32_f16(qf[qs][0], kf0, sacc[qs][ks], 0, 0, 0);
        sacc[qs][ks] = __builtin_amdgcn_mfma_f32_16x16x32_f16(qf[qs][1], kf1, sacc[qs][ks], 0, 0, 0);
      }
    }

    // online softmax in log2 domain; rows owned by 16 lanes -> shfl_xor 1..8
#pragma unroll
    for (int qs = 0; qs < 2; qs++) {
#pragma unroll
      for (int r = 0; r < 4; r++) {
        float mx = fmaxf(fmaxf(sacc[qs][0][r], sacc[qs][1][r]),
                         fmaxf(sacc[qs][2][r], sacc[qs][3][r]));
        for (int d = 1; d < 16; d <<= 1) mx = fmaxf(mx, __shfl_xor(mx, d, 64));
        mx *= SC2;
        float mold = mrow[qs][r];
        float mnew = fmaxf(mold, mx);
        mrow[qs][r] = mnew;
        float alpha = exp2f(mold - mnew);   // mold=-1e30 -> 0
        lrow[qs][r] *= alpha;
#pragma unroll
        for (int dt = 0; dt < 4; dt++) oacc[qs][dt][r] *= alpha;
      }
#pragma unroll
      for (int ks = 0; ks < 4; ks++) {
#pragma unroll
        for (int r = 0; r < 4; r++) {
          float p = exp2f(sacc[qs][ks][r] * SC2 - mrow[qs][r]);
          lrow[qs][r] += p;   // lane-partial rowsum; reduced at finalize
          sP[(wave * 32 + qs * 16 + quad * 4 + r) * 72 + ks * 16 + l16] = (f16)p;
        }
      }
    }
    __syncthreads();

    // O += P V   (B-frag from swizzled sVt)
#pragma unroll
    for (int kk = 0; kk < 2; kk++) {
      f16x8 pf[2];
#pragma unroll
      for (int qs = 0; qs < 2; qs++)
        pf[qs] = *(const f16x8*)&sP[(wave * 32 + qs * 16 + l16) * 72 + kk * 32 + quad * 8];
#pragma unroll
      for (int dt = 0; dt < 4; dt++) {
        int d = dt * 16 + l16;
        f16x8 vf = *(const f16x8*)&sVt[d * 72 + ((kk * 32 + quad * 8) ^ (d & 56))];
#pragma unroll
        for (int qs = 0; qs < 2; qs++)
          oacc[qs][dt] = __builtin_amdgcn_mfma_f32_16x16x32_f16(pf[qs], vf, oacc[qs][dt], 0, 0, 0);
      }
    }
    __syncthreads();
  }

  // finalize: reduce lane-partial l across the 16 lanes, divide, store
  f16* Ob = O + (size_t)b * bstride + h * 64;
#pragma unroll
  for (int qs = 0; qs < 2; qs++) {
#pragma unroll
    for (int r = 0; r < 4; r++) {
      float l = lrow[qs][r];
      for (int d = 1; d < 16; d <<= 1) l += __shfl_xor(l, d, 64);
      float inv = 1.0f / l;
      int qr = wave * 32 + qs * 16 + quad * 4 + r;
      int s = (nth_i * 8 + (qr >> 4)) * 64 + ntw_i * 16 + (qr & 15);
#pragma unroll
      for (int dt = 0; dt < 4; dt++)
        Ob[(size_t)s * K_HID + dt * 16 + l16] = (f16)(oacc[qs][dt][r] * inv);
    }
  }
}

extern "C" void kernel_launch(void* const* d_in, const int* in_sizes, int n_in,
                              void* d_out, int out_size, void* d_ws, size_t ws_size,
                              hipStream_t stream) {
  const float* hs = (const float*)d_in[0];
  const float* Wq = (const float*)d_in[1];
  const float* Wk = (const float*)d_in[2];
  const float* Wv = (const float*)d_in[3];
  const float* Wo = (const float*)d_in[4];
  float* out = (float*)d_out;

  char* ws = (char*)d_ws;
  const size_t WELEM = (size_t)K_HID * K_HID;      // 4,194,304
  const size_t XELEM = (size_t)M_ROWS * K_HID;     // 16,777,216
  f16* WT = (f16*)ws;  ws += 4 * WELEM * sizeof(f16);  // WqT,WkT,WvT,WoT
  f16* Xh = (f16*)ws;  ws += XELEM * sizeof(f16);
  f16* Qb = (f16*)ws;  ws += XELEM * sizeof(f16);      // Q,K,V contiguous
  f16* Kb = (f16*)ws;  ws += XELEM * sizeof(f16);
  f16* Vb = (f16*)ws;  ws += XELEM * sizeof(f16);
  f16* Ob = (f16*)ws;  ws += XELEM * sizeof(f16);

  cvt_f32_to_f16<<<(int)(XELEM / (256 * 8)), 256, 0, stream>>>(hs, Xh, (int)XELEM);
  transpose_cvt<<<dim3(64, 64, 4), 256, 0, stream>>>(Wq, Wk, Wv, Wo, WT);
  gemm_bt<f16><<<dim3(8, 32, 3), 512, 0, stream>>>(Xh, WT, Qb, M_ROWS, K_HID, K_HID,
                                                   WELEM, XELEM);
  attn_kernel<<<dim3(32, 32, 2), 256, 0, stream>>>(Qb, Kb, Vb, Ob);
  gemm_bt<float><<<dim3(8, 32, 1), 512, 0, stream>>>(Ob, WT + 3 * WELEM, out,
                                                     M_ROWS, K_HID, K_HID, 0, 0);
}

// Round 4
// 524.818 us; speedup vs baseline: 1.1326x; 1.1326x over previous
//
#include <hip/hip_runtime.h>
#include <math.h>

typedef _Float16 f16;
typedef _Float16 f16x2 __attribute__((ext_vector_type(2)));
typedef _Float16 f16x4 __attribute__((ext_vector_type(4)));
typedef _Float16 f16x8 __attribute__((ext_vector_type(8)));
typedef float f32x4 __attribute__((ext_vector_type(4)));

#define K_HID 2048
#define N_SEQ 4096
#define N_BATCH 2
#define M_ROWS 8192   // B*S

// async global->LDS, 16B per lane. LDS dest must be WAVE-UNIFORM base;
// HW writes lane i at base + i*16 (lane-contiguous, no padding allowed).
__device__ __forceinline__ void gl2lds16(const f16* g, f16* l) {
  auto gp = (const __attribute__((address_space(1))) unsigned*)(unsigned long long)(uintptr_t)g;
  auto lp = (__attribute__((address_space(3))) unsigned*)(unsigned)(uintptr_t)l;
  __builtin_amdgcn_global_load_lds(gp, lp, 16, 0, 0);
}

// ---------------- f32 -> f16 conversion (8 elems/thread) ----------------
__global__ __launch_bounds__(256) void cvt_f32_to_f16(const float* __restrict__ x,
                                                      f16* __restrict__ y, int n) {
  int i = (blockIdx.x * 256 + threadIdx.x) * 8;
  if (i >= n) return;
  float4 a = *(const float4*)(x + i);
  float4 b = *(const float4*)(x + i + 4);
  f16x8 o;
  o[0] = (f16)a.x; o[1] = (f16)a.y; o[2] = (f16)a.z; o[3] = (f16)a.w;
  o[4] = (f16)b.x; o[5] = (f16)b.y; o[6] = (f16)b.z; o[7] = (f16)b.w;
  *(f16x8*)(y + i) = o;
}

// -------- weight transpose+convert: W[K][N] f32 -> Wt[N][K] f16 ----------
__global__ __launch_bounds__(256) void transpose_cvt(const float* __restrict__ W0,
                                                     const float* __restrict__ W1,
                                                     const float* __restrict__ W2,
                                                     const float* __restrict__ W3,
                                                     f16* __restrict__ WT) {
  const float* W = (blockIdx.z == 0) ? W0 : (blockIdx.z == 1) ? W1
                 : (blockIdx.z == 2) ? W2 : W3;
  f16* Wt = WT + (size_t)blockIdx.z * K_HID * K_HID;
  __shared__ float tile[32][33];
  int bx = blockIdx.x * 32;   // n base
  int by = blockIdx.y * 32;   // k base
  int x = threadIdx.x & 31;
  int y = threadIdx.x >> 5;   // 0..7
  for (int i = 0; i < 32; i += 8)
    tile[y + i][x] = W[(size_t)(by + y + i) * K_HID + bx + x];
  __syncthreads();
  for (int i = 0; i < 32; i += 8)
    Wt[(size_t)(bx + y + i) * K_HID + by + x] = (f16)tile[x][y + i];
}

// ---------------- GEMM: C[M][N] = A[M][K] * Bt[N][K]^T ----------------
// (round-2 winner, reverted: 206 us QKV, MfmaUtil 44.7%, 0 bank conflicts)
// 256x256 tile, BK=64, 512 threads = 8 waves (2M x 4N), per-wave 128x64 out.
// Double-buffered 128 KiB LDS; counted-vmcnt pipeline: stage next K-tile's A
// before the barrier, wait vmcnt(4) so those loads stay in flight ACROSS the
// raw s_barrier; stage B mid-iteration under the first MFMA half. setprio(1)
// wraps the MFMA clusters. LDS linear (gl2lds) with pre-swizzled global
// source chunk^=(row&7): 128B row stride + 3-bit XOR -> 8 chunk positions
// x 2 lanes = conflict-free b128 reads. (Round-3 lesson: 64B stride kills
// this -> 8-way conflicts; keep 128B+XOR.)
template <typename OutT>
__global__ __launch_bounds__(512, 2) void gemm_bt(const f16* __restrict__ A,
                                                  const f16* __restrict__ BtBase,
                                                  OutT* __restrict__ CBase,
                                                  int M, int N, int Kd,
                                                  size_t bzStride, size_t czStride) {
  const f16* Bt = BtBase + bzStride * blockIdx.z;
  OutT* C = CBase + czStride * blockIdx.z;
  __shared__ f16 sA[2][256 * 64];   // 32 KiB per buffer
  __shared__ f16 sB[2][256 * 64];
  int tid = threadIdx.x;
  int lane = tid & 63, wave = tid >> 6;          // 8 waves
  int quad = lane >> 4, l16 = lane & 15;
  int mBase = blockIdx.y * 256, nBase = blockIdx.x * 256;
  int wm = (wave >> 2) * 128, wn = (wave & 3) * 64;

  f32x4 acc[8][4];
#pragma unroll
  for (int mf = 0; mf < 8; mf++)
#pragma unroll
    for (int nf = 0; nf < 4; nf++) acc[mf][nf] = (f32x4){0.f, 0.f, 0.f, 0.f};

  // staging: wave w covers rows [32w, 32w+32) of the A and B tiles, as
  // 4 gl2lds of 8 rows (1 KiB) each. lane -> row r8 = lane>>3, global
  // chunk (lane&7)^r8 (pre-swizzle; LDS destination stays lane-linear).
  int r8 = lane >> 3;
  int csw = ((lane & 7) ^ r8) * 8;
  const f16* Ag = A + (size_t)(mBase + wave * 32 + r8) * Kd + csw;
  const f16* Bg = Bt + (size_t)(nBase + wave * 32 + r8) * Kd + csw;

  f16* lA0 = &sA[0][wave * 2048];
  f16* lA1 = &sA[1][wave * 2048];
  f16* lB0 = &sB[0][wave * 2048];
  f16* lB1 = &sB[1][wave * 2048];

#define STAGE_A(dst, t)                                                  \
  { _Pragma("unroll") for (int q = 0; q < 4; ++q)                        \
      gl2lds16(Ag + (size_t)(q * 8) * Kd + (size_t)(t) * 64, (dst) + q * 512); }
#define STAGE_B(dst, t)                                                  \
  { _Pragma("unroll") for (int q = 0; q < 4; ++q)                        \
      gl2lds16(Bg + (size_t)(q * 8) * Kd + (size_t)(t) * 64, (dst) + q * 512); }

  // fragment reads: global chunk cw for row r lives at LDS chunk cw^(r&7)
  int aRow = (wm + l16) * 64;
  int bRow = (wn + l16) * 64;
  int c0 = (quad ^ (l16 & 7)) * 8;   // k-step 0 (k in [quad*8, +8))
  int c1 = c0 ^ 32;                  // k-step 1 (chunk ^ 4)

  const int NT = Kd >> 6;   // 64-wide K-tiles
  STAGE_A(lA0, 0);
  STAGE_B(lB0, 0);

  const f16* sAc = &sA[0][0]; const f16* sAo = &sA[1][0];
  const f16* sBc = &sB[0][0]; const f16* sBo = &sB[1][0];
  f16* lAn = lA1; f16* lAo = lA0;
  f16* lBn = lB1; f16* lBo = lB0;

  for (int t = 0; t < NT; ++t) {
    if (t + 1 < NT) {
      STAGE_A(lAn, t + 1);
      // outstanding: A(t) 4 + B(t) 4 + A(t+1) 4 -> wait until only A(t+1)
      // remains in flight across the barrier.
      asm volatile("s_waitcnt vmcnt(4)" ::: "memory");
    } else {
      asm volatile("s_waitcnt vmcnt(0)" ::: "memory");
    }
    __builtin_amdgcn_s_barrier();
    __builtin_amdgcn_sched_barrier(0);   // pin ds_reads below the barrier

    f16x8 bf[4][2], af[4][2];
#pragma unroll
    for (int nf = 0; nf < 4; nf++) {
      bf[nf][0] = *(const f16x8*)&sBc[bRow + nf * 1024 + c0];
      bf[nf][1] = *(const f16x8*)&sBc[bRow + nf * 1024 + c1];
    }
#pragma unroll
    for (int mf = 0; mf < 4; mf++) {
      af[mf][0] = *(const f16x8*)&sAc[aRow + mf * 1024 + c0];
      af[mf][1] = *(const f16x8*)&sAc[aRow + mf * 1024 + c1];
    }
    __builtin_amdgcn_s_setprio(1);
#pragma unroll
    for (int mf = 0; mf < 4; mf++)
#pragma unroll
      for (int nf = 0; nf < 4; nf++) {
        acc[mf][nf] = __builtin_amdgcn_mfma_f32_16x16x32_f16(af[mf][0], bf[nf][0], acc[mf][nf], 0, 0, 0);
        acc[mf][nf] = __builtin_amdgcn_mfma_f32_16x16x32_f16(af[mf][1], bf[nf][1], acc[mf][nf], 0, 0, 0);
      }
    __builtin_amdgcn_s_setprio(0);

    if (t + 1 < NT) STAGE_B(lBn, t + 1);   // B latency hides under MFMA half 2

#pragma unroll
    for (int mf = 0; mf < 4; mf++) {
      af[mf][0] = *(const f16x8*)&sAc[aRow + 4096 + mf * 1024 + c0];
      af[mf][1] = *(const f16x8*)&sAc[aRow + 4096 + mf * 1024 + c1];
    }
    __builtin_amdgcn_s_setprio(1);
#pragma unroll
    for (int mf = 0; mf < 4; mf++)
#pragma unroll
      for (int nf = 0; nf < 4; nf++) {
        acc[mf + 4][nf] = __builtin_amdgcn_mfma_f32_16x16x32_f16(af[mf][0], bf[nf][0], acc[mf + 4][nf], 0, 0, 0);
        acc[mf + 4][nf] = __builtin_amdgcn_mfma_f32_16x16x32_f16(af[mf][1], bf[nf][1], acc[mf + 4][nf], 0, 0, 0);
      }
    __builtin_amdgcn_s_setprio(0);
    __builtin_amdgcn_sched_barrier(0);   // keep reads above the barrier
    __builtin_amdgcn_s_barrier();        // buf cur now dead -> restageable

    { const f16* tt;
      tt = sAc; sAc = sAo; sAo = tt;
      tt = sBc; sBc = sBo; sBo = tt; }
    { f16* tt;
      tt = lAn; lAn = lAo; lAo = tt;
      tt = lBn; lBn = lBo; lBo = tt; }
  }
#undef STAGE_A
#undef STAGE_B

#pragma unroll
  for (int mf = 0; mf < 8; mf++) {
    int row = mBase + wm + mf * 16 + quad * 4;
#pragma unroll
    for (int nf = 0; nf < 4; nf++) {
      int col = nBase + wn + nf * 16 + l16;
      OutT* Cp = C + (size_t)row * N + col;
#pragma unroll
      for (int r = 0; r < 4; r++) Cp[(size_t)r * N] = (OutT)acc[mf][nf][r];
    }
  }
}

// ---------------- sliding-tile flash attention (swapped-operand) ----------
// grid (T=32 tiles, NH=32, B=2), 256 threads = 4 waves, 32 q-rows each.
// Swapped QK^T: S^T = mfma(K-frag, Q-frag) -> lane l16 owns ONE q column:
// row-max/sum are 15 in-lane fmax + 2 shfl_xor (vs 32 shfls before); P is
// written packed (f16x4, b64) to sPt[q][k]; PV is O^T = mfma(V^T, P^T).
// Q is staged through sPt (freed before first P write) -> LDS 36.9 KB ->
// 4 blocks/CU (16 waves) vs 2 before. sVt keeps col ^= (d&56) XOR swizzle;
// V staged in token pairs (f16x2 writes, 2-way-free).
__global__ __launch_bounds__(256) void attn_kernel(const f16* __restrict__ Q,
                                                   const f16* __restrict__ Kg,
                                                   const f16* __restrict__ V,
                                                   f16* __restrict__ O) {
  __shared__ f16 sK[64 * 72];
  __shared__ f16 sVt[64 * 72];    // V transposed: [d][k ^ (d&56)]
  __shared__ f16 sPt[128 * 72];   // P[q][k] packed; also Q staging buffer

  int t = blockIdx.x, h = blockIdx.y, b = blockIdx.z;
  int nth_i = t >> 2, ntw_i = t & 3;    // Ht=8, Wt=4
  int tid = threadIdx.x;
  int lane = tid & 63, wave = tid >> 6;
  int quad = lane >> 4, l16 = lane & 15;
  const size_t bstride = (size_t)N_SEQ * K_HID;
  const f16* Qb = Q + (size_t)b * bstride + h * 64;
  const f16* Kb = Kg + (size_t)b * bstride + h * 64;
  const f16* Vb = V + (size_t)b * bstride + h * 64;

  const float SC2 = 0.18033688f;   // (1/sqrt(64)) * log2(e)

  // stage Q tile [128 x 64] via sPt: row qr -> token s
  for (int i = tid; i < 1024; i += 256) {
    int qr = i >> 3, dc = (i & 7) * 8;
    int s = (nth_i * 8 + (qr >> 4)) * 64 + ntw_i * 16 + (qr & 15);
    *(float4*)&sPt[qr * 72 + dc] = *(const float4*)&Qb[(size_t)s * K_HID + dc];
  }
  __syncthreads();

  f16x8 qf[2][2];   // [q-subtile][d-half]; identical layout as A or B operand
#pragma unroll
  for (int qs = 0; qs < 2; qs++)
#pragma unroll
    for (int kk = 0; kk < 2; kk++)
      qf[qs][kk] = *(const f16x8*)&sPt[(wave * 32 + qs * 16 + l16) * 72 + kk * 32 + quad * 8];
  // qf reads drain at chunk-0's post-stage __syncthreads before sPt reuse.

  f32x4 oacc[2][4];   // O^T: [qs][dt], col=l16=q, row=quad*4+r=d within dt
#pragma unroll
  for (int qs = 0; qs < 2; qs++)
#pragma unroll
    for (int dt = 0; dt < 4; dt++) oacc[qs][dt] = (f32x4){0.f, 0.f, 0.f, 0.f};
  float mrow[2] = {-1e30f, -1e30f};
  float lrow[2] = {0.f, 0.f};   // quad-partial rowsum; reduced at finalize

  int cr = min(max(nth_i, 1), 7);   // clamped window center (tile units)
  int cc = min(max(ntw_i, 1), 3);

  for (int c = 0; c < 8; c++) {
    int kt = c >> 1, half = c & 1;
    int ti = cr - 1 + (kt >> 1), tj = cc - 1 + (kt & 1);
    // stage K chunk [64 x 64] (row-major, +72 pad)
    for (int i = tid; i < 512; i += 256) {
      int kl = i >> 3, dc = (i & 7) * 8;
      int kr = half * 64 + kl;
      int s = (ti * 8 + (kr >> 4)) * 64 + tj * 16 + (kr & 15);
      *(float4*)&sK[kl * 72 + dc] = *(const float4*)&Kb[(size_t)s * K_HID + dc];
    }
    // stage swizzled V^T in token PAIRS: thread -> (pair, d-chunk), 8 f16x2
    {
      int pr = tid >> 3, dc = (tid & 7) * 8;
      int k0 = pr * 2;
      int kr0 = half * 64 + k0, kr1 = kr0 + 1;
      int s0 = (ti * 8 + (kr0 >> 4)) * 64 + tj * 16 + (kr0 & 15);
      int s1 = (ti * 8 + (kr1 >> 4)) * 64 + tj * 16 + (kr1 & 15);
      f16x8 v0 = *(const f16x8*)&Vb[(size_t)s0 * K_HID + dc];
      f16x8 v1 = *(const f16x8*)&Vb[(size_t)s1 * K_HID + dc];
      int swc = k0 ^ dc;   // dc == (d & 56) for rows dc..dc+7; k0 even
#pragma unroll
      for (int j = 0; j < 8; j++) {
        f16x2 pv; pv[0] = v0[j]; pv[1] = v1[j];
        *(f16x2*)&sVt[(dc + j) * 72 + swc] = pv;
      }
    }
    __syncthreads();

    // S^T = K Q^T: sacc[qs][ks] col=l16=q, row=quad*4+r=k within ks block
    f32x4 sacc[2][4];
#pragma unroll
    for (int qs = 0; qs < 2; qs++)
#pragma unroll
      for (int ks = 0; ks < 4; ks++) sacc[qs][ks] = (f32x4){0.f, 0.f, 0.f, 0.f};
#pragma unroll
    for (int ks = 0; ks < 4; ks++) {
      f16x8 kf0 = *(const f16x8*)&sK[(ks * 16 + l16) * 72 + quad * 8];
      f16x8 kf1 = *(const f16x8*)&sK[(ks * 16 + l16) * 72 + 32 + quad * 8];
#pragma unroll
      for (int qs = 0; qs < 2; qs++) {
        sacc[qs][ks] = __builtin_amdgcn_mfma_f32_16x16x32_f16(kf0, qf[qs][0], sacc[qs][ks], 0, 0, 0);
        sacc[qs][ks] = __builtin_amdgcn_mfma_f32_16x16x32_f16(kf1, qf[qs][1], sacc[qs][ks], 0, 0, 0);
      }
    }

    // online softmax: lane owns q = l16; in-lane max over 16 + 2 cross-quad
#pragma unroll
    for (int qs = 0; qs < 2; qs++) {
      float mx = sacc[qs][0][0];
#pragma unroll
      for (int ks = 0; ks < 4; ks++)
#pragma unroll
        for (int r = 0; r < 4; r++) mx = fmaxf(mx, sacc[qs][ks][r]);
      mx = fmaxf(mx, __shfl_xor(mx, 16, 64));
      mx = fmaxf(mx, __shfl_xor(mx, 32, 64));
      mx *= SC2;
      float mold = mrow[qs];
      float mnew = fmaxf(mold, mx);
      mrow[qs] = mnew;
      float alpha = exp2f(mold - mnew);   // mold=-1e30 -> 0
      lrow[qs] *= alpha;
#pragma unroll
      for (int dt = 0; dt < 4; dt++)
#pragma unroll
        for (int r = 0; r < 4; r++) oacc[qs][dt][r] *= alpha;
      float ls = 0.f;
      int qrow = (wave * 32 + qs * 16 + l16) * 72;
#pragma unroll
      for (int ks = 0; ks < 4; ks++) {
        f16x4 pk;
#pragma unroll
        for (int r = 0; r < 4; r++) {
          float p = exp2f(sacc[qs][ks][r] * SC2 - mnew);
          ls += p;
          pk[r] = (f16)p;
        }
        *(f16x4*)&sPt[qrow + ks * 16 + quad * 4] = pk;   // P[q][k] b64 write
      }
      lrow[qs] += ls;
    }
    __syncthreads();

    // O^T += V^T P^T: A = V^T frag (rows d), B = P^T frag (cols q)
#pragma unroll
    for (int kk = 0; kk < 2; kk++) {
      f16x8 pf[2];
#pragma unroll
      for (int qs = 0; qs < 2; qs++)
        pf[qs] = *(const f16x8*)&sPt[(wave * 32 + qs * 16 + l16) * 72 + kk * 32 + quad * 8];
#pragma unroll
      for (int dt = 0; dt < 4; dt++) {
        int d = dt * 16 + l16;
        f16x8 vf = *(const f16x8*)&sVt[d * 72 + ((kk * 32 + quad * 8) ^ (d & 56))];
#pragma unroll
        for (int qs = 0; qs < 2; qs++)
          oacc[qs][dt] = __builtin_amdgcn_mfma_f32_16x16x32_f16(vf, pf[qs], oacc[qs][dt], 0, 0, 0);
      }
    }
    __syncthreads();
  }

  // finalize: cross-quad l reduce (2 shfl), divide, packed b64 stores
  f16* Ob = O + (size_t)b * bstride + h * 64;
#pragma unroll
  for (int qs = 0; qs < 2; qs++) {
    float l = lrow[qs];
    l += __shfl_xor(l, 16, 64);
    l += __shfl_xor(l, 32, 64);
    float inv = 1.0f / l;
    int q = wave * 32 + qs * 16 + l16;
    int s = (nth_i * 8 + (q >> 4)) * 64 + ntw_i * 16 + (q & 15);
#pragma unroll
    for (int dt = 0; dt < 4; dt++) {
      f16x4 ok;
#pragma unroll
      for (int r = 0; r < 4; r++) ok[r] = (f16)(oacc[qs][dt][r] * inv);
      *(f16x4*)&Ob[(size_t)s * K_HID + dt * 16 + quad * 4] = ok;
    }
  }
}

extern "C" void kernel_launch(void* const* d_in, const int* in_sizes, int n_in,
                              void* d_out, int out_size, void* d_ws, size_t ws_size,
                              hipStream_t stream) {
  const float* hs = (const float*)d_in[0];
  const float* Wq = (const float*)d_in[1];
  const float* Wk = (const float*)d_in[2];
  const float* Wv = (const float*)d_in[3];
  const float* Wo = (const float*)d_in[4];
  float* out = (float*)d_out;

  char* ws = (char*)d_ws;
  const size_t WELEM = (size_t)K_HID * K_HID;      // 4,194,304
  const size_t XELEM = (size_t)M_ROWS * K_HID;     // 16,777,216
  f16* WT = (f16*)ws;  ws += 4 * WELEM * sizeof(f16);  // WqT,WkT,WvT,WoT
  f16* Xh = (f16*)ws;  ws += XELEM * sizeof(f16);
  f16* Qb = (f16*)ws;  ws += XELEM * sizeof(f16);      // Q,K,V contiguous
  f16* Kb = (f16*)ws;  ws += XELEM * sizeof(f16);
  f16* Vb = (f16*)ws;  ws += XELEM * sizeof(f16);
  f16* Ob = (f16*)ws;  ws += XELEM * sizeof(f16);

  cvt_f32_to_f16<<<(int)(XELEM / (256 * 8)), 256, 0, stream>>>(hs, Xh, (int)XELEM);
  transpose_cvt<<<dim3(64, 64, 4), 256, 0, stream>>>(Wq, Wk, Wv, Wo, WT);
  gemm_bt<f16><<<dim3(8, 32, 3), 512, 0, stream>>>(Xh, WT, Qb, M_ROWS, K_HID, K_HID,
                                                   WELEM, XELEM);
  attn_kernel<<<dim3(32, 32, 2), 256, 0, stream>>>(Qb, Kb, Vb, Ob);
  gemm_bt<float><<<dim3(8, 32, 1), 512, 0, stream>>>(Ob, WT + 3 * WELEM, out,
                                                     M_ROWS, K_HID, K_HID, 0, 0);
}

// Round 5
// 521.496 us; speedup vs baseline: 1.1398x; 1.0064x over previous
//
#include <hip/hip_runtime.h>
#include <math.h>

typedef _Float16 f16;
typedef _Float16 f16x2 __attribute__((ext_vector_type(2)));
typedef _Float16 f16x4 __attribute__((ext_vector_type(4)));
typedef _Float16 f16x8 __attribute__((ext_vector_type(8)));
typedef float f32x4 __attribute__((ext_vector_type(4)));

#define K_HID 2048
#define N_SEQ 4096
#define N_BATCH 2
#define M_ROWS 8192   // B*S

// async global->LDS, 16B per lane. LDS dest must be WAVE-UNIFORM base;
// HW writes lane i at base + i*16 (lane-contiguous, no padding allowed).
__device__ __forceinline__ void gl2lds16(const f16* g, f16* l) {
  auto gp = (const __attribute__((address_space(1))) unsigned*)(unsigned long long)(uintptr_t)g;
  auto lp = (__attribute__((address_space(3))) unsigned*)(unsigned)(uintptr_t)l;
  __builtin_amdgcn_global_load_lds(gp, lp, 16, 0, 0);
}

// ---------------- f32 -> f16 conversion (8 elems/thread) ----------------
__global__ __launch_bounds__(256) void cvt_f32_to_f16(const float* __restrict__ x,
                                                      f16* __restrict__ y, int n) {
  int i = (blockIdx.x * 256 + threadIdx.x) * 8;
  if (i >= n) return;
  float4 a = *(const float4*)(x + i);
  float4 b = *(const float4*)(x + i + 4);
  f16x8 o;
  o[0] = (f16)a.x; o[1] = (f16)a.y; o[2] = (f16)a.z; o[3] = (f16)a.w;
  o[4] = (f16)b.x; o[5] = (f16)b.y; o[6] = (f16)b.z; o[7] = (f16)b.w;
  *(f16x8*)(y + i) = o;
}

// -------- weight transpose+convert: W[K][N] f32 -> Wt[N][K] f16 ----------
__global__ __launch_bounds__(256) void transpose_cvt(const float* __restrict__ W0,
                                                     const float* __restrict__ W1,
                                                     const float* __restrict__ W2,
                                                     const float* __restrict__ W3,
                                                     f16* __restrict__ WT) {
  const float* W = (blockIdx.z == 0) ? W0 : (blockIdx.z == 1) ? W1
                 : (blockIdx.z == 2) ? W2 : W3;
  f16* Wt = WT + (size_t)blockIdx.z * K_HID * K_HID;
  __shared__ float tile[32][33];
  int bx = blockIdx.x * 32;   // n base
  int by = blockIdx.y * 32;   // k base
  int x = threadIdx.x & 31;
  int y = threadIdx.x >> 5;   // 0..7
  for (int i = 0; i < 32; i += 8)
    tile[y + i][x] = W[(size_t)(by + y + i) * K_HID + bx + x];
  __syncthreads();
  for (int i = 0; i < 32; i += 8)
    Wt[(size_t)(bx + y + i) * K_HID + by + x] = (f16)tile[x][y + i];
}

// ---------------- GEMM: C[M][N] = A[M][K] * Bt[N][K]^T ----------------
// 256x256 tile, BK=64, 512 threads = 8 waves (2M x 4N), per-wave 128x64 out.
// LDS layout IDENTICAL to the round-2 winner (128B row stride, 3-bit XOR
// chunk pre-swizzle on the global source, lane-linear gl2lds dest ->
// conflict-free b128 reads; round-3 lesson: do NOT touch this layout).
// NEW: 4 output-quadrant phases per K-tile (m-half x n-half, 16 MFMA each)
// with phase-aligned staging bands and counted vmcnt (T3+T4):
//   stage order per tile: A-ph0set(2), B-ph0set(2), B-ph1set(2), A-ph2set(2)
//   ph0: +2 stage, vmcnt(6) -> A0+B0 landed; ph1: +2, vmcnt(6) -> B1;
//   ph2: +2, vmcnt(6) -> A1; ph3: +2, no wait. Never drains below 6 in the
//   main loop; epilogue 4 -> 2 -> 0. Bands are re-mapped so L1..L4 cover
//   exactly the ph0 row-sets, etc. setprio(1) wraps each MFMA cluster.
template <typename OutT>
__global__ __launch_bounds__(512, 2) void gemm_bt(const f16* __restrict__ A,
                                                  const f16* __restrict__ BtBase,
                                                  OutT* __restrict__ CBase,
                                                  int M, int N, int Kd,
                                                  size_t bzStride, size_t czStride) {
  const f16* Bt = BtBase + bzStride * blockIdx.z;
  OutT* C = CBase + czStride * blockIdx.z;
  __shared__ f16 sA[2][256 * 64];   // 32 KiB per buffer
  __shared__ f16 sB[2][256 * 64];
  int tid = threadIdx.x;
  int lane = tid & 63, wave = tid >> 6;          // 8 waves
  int quad = lane >> 4, l16 = lane & 15;
  int mBase = blockIdx.y * 256, nBase = blockIdx.x * 256;
  int wm = (wave >> 2) * 128, wn = (wave & 3) * 64;

  f32x4 acc[8][4];
#pragma unroll
  for (int mf = 0; mf < 8; mf++)
#pragma unroll
    for (int nf = 0; nf < 4; nf++) acc[mf][nf] = (f32x4){0.f, 0.f, 0.f, 0.f};

  // staging geometry: one gl2lds = one 8-row band (1 KiB). lane -> row
  // r8 = lane>>3 within band, global chunk (lane&7)^r8 (pre-swizzle; LDS
  // dest lane-linear). Band assignment is PHASE-ALIGNED:
  //   A: j0:w      j1:16+w   (ph0 rows {0-63,128-191})
  //      j2:8+w    j3:24+w   (ph2 rows {64-127,192-255})
  //   B: base=(w&3)+((w>>2)<<3)
  //      j0:base   j1:base+16 (ph0/ph3 n-bands, (b&4)==0)
  //      j2:base+4 j3:base+20 (ph1/ph2 n-bands, (b&4)==4)
  int r8 = lane >> 3;
  int csw = ((lane & 7) ^ r8) * 8;
  int bA0 = wave, bA1 = wave + 16, bA2 = wave + 8, bA3 = wave + 24;
  int bBb = (wave & 3) + ((wave >> 2) << 3);
  int bB0 = bBb, bB1 = bBb + 16, bB2 = bBb + 4, bB3 = bBb + 20;
  const f16* AgJ0 = A + (size_t)(mBase + bA0 * 8 + r8) * Kd + csw;
  const f16* AgJ1 = A + (size_t)(mBase + bA1 * 8 + r8) * Kd + csw;
  const f16* AgJ2 = A + (size_t)(mBase + bA2 * 8 + r8) * Kd + csw;
  const f16* AgJ3 = A + (size_t)(mBase + bA3 * 8 + r8) * Kd + csw;
  const f16* BgJ0 = Bt + (size_t)(nBase + bB0 * 8 + r8) * Kd + csw;
  const f16* BgJ1 = Bt + (size_t)(nBase + bB1 * 8 + r8) * Kd + csw;
  const f16* BgJ2 = Bt + (size_t)(nBase + bB2 * 8 + r8) * Kd + csw;
  const f16* BgJ3 = Bt + (size_t)(nBase + bB3 * 8 + r8) * Kd + csw;

#define STG_A01(buf, tt) { gl2lds16(AgJ0 + (size_t)(tt) * 64, (buf) + bA0 * 512); \
                           gl2lds16(AgJ1 + (size_t)(tt) * 64, (buf) + bA1 * 512); }
#define STG_A23(buf, tt) { gl2lds16(AgJ2 + (size_t)(tt) * 64, (buf) + bA2 * 512); \
                           gl2lds16(AgJ3 + (size_t)(tt) * 64, (buf) + bA3 * 512); }
#define STG_B01(buf, tt) { gl2lds16(BgJ0 + (size_t)(tt) * 64, (buf) + bB0 * 512); \
                           gl2lds16(BgJ1 + (size_t)(tt) * 64, (buf) + bB1 * 512); }
#define STG_B23(buf, tt) { gl2lds16(BgJ2 + (size_t)(tt) * 64, (buf) + bB2 * 512); \
                           gl2lds16(BgJ3 + (size_t)(tt) * 64, (buf) + bB3 * 512); }

  // fragment reads: global chunk cw for row r lives at LDS chunk cw^(r&7)
  int aRow = (wm + l16) * 64;
  int bRow = (wn + l16) * 64;
  int c0 = (quad ^ (l16 & 7)) * 8;   // k-step 0 (k in [quad*8, +8))
  int c1 = c0 ^ 32;                  // k-step 1

  const int NT = Kd >> 6;   // 64-wide K-tiles

  f16* cA = &sA[0][0]; f16* nA = &sA[1][0];
  f16* cB = &sB[0][0]; f16* nB = &sB[1][0];

  // prologue: stage tile 0 in the canonical order (8 loads outstanding)
  STG_A01(cA, 0); STG_B01(cB, 0); STG_B23(cB, 0); STG_A23(cA, 0);

  for (int t = 0; t < NT; ++t) {
    const bool pre = (t + 1 < NT);
    f16x8 af[4][2], bf[2][2];
    // ---------- phase 0: (m 0-3, n 0-1) ----------
    if (pre) STG_A01(nA, t + 1);
    if (pre) asm volatile("s_waitcnt vmcnt(6)" ::: "memory");
    else     asm volatile("s_waitcnt vmcnt(4)" ::: "memory");
    __builtin_amdgcn_s_barrier();
    __builtin_amdgcn_sched_barrier(0);
#pragma unroll
    for (int mf = 0; mf < 4; mf++) {
      af[mf][0] = *(const f16x8*)&cA[aRow + mf * 1024 + c0];
      af[mf][1] = *(const f16x8*)&cA[aRow + mf * 1024 + c1];
    }
#pragma unroll
    for (int nf = 0; nf < 2; nf++) {
      bf[nf][0] = *(const f16x8*)&cB[bRow + nf * 1024 + c0];
      bf[nf][1] = *(const f16x8*)&cB[bRow + nf * 1024 + c1];
    }
    asm volatile("s_waitcnt lgkmcnt(0)" ::: "memory");
    __builtin_amdgcn_sched_barrier(0);
    __builtin_amdgcn_s_setprio(1);
#pragma unroll
    for (int mf = 0; mf < 4; mf++)
#pragma unroll
      for (int nf = 0; nf < 2; nf++) {
        acc[mf][nf] = __builtin_amdgcn_mfma_f32_16x16x32_f16(af[mf][0], bf[nf][0], acc[mf][nf], 0, 0, 0);
        acc[mf][nf] = __builtin_amdgcn_mfma_f32_16x16x32_f16(af[mf][1], bf[nf][1], acc[mf][nf], 0, 0, 0);
      }
    __builtin_amdgcn_s_setprio(0);
    __builtin_amdgcn_s_barrier();
    // ---------- phase 1: (m 0-3, n 2-3), af kept ----------
    if (pre) STG_B01(nB, t + 1);
    if (pre) asm volatile("s_waitcnt vmcnt(6)" ::: "memory");
    else     asm volatile("s_waitcnt vmcnt(2)" ::: "memory");
    __builtin_amdgcn_s_barrier();
    __builtin_amdgcn_sched_barrier(0);
#pragma unroll
    for (int nf = 0; nf < 2; nf++) {
      bf[nf][0] = *(const f16x8*)&cB[bRow + (nf + 2) * 1024 + c0];
      bf[nf][1] = *(const f16x8*)&cB[bRow + (nf + 2) * 1024 + c1];
    }
    asm volatile("s_waitcnt lgkmcnt(0)" ::: "memory");
    __builtin_amdgcn_sched_barrier(0);
    __builtin_amdgcn_s_setprio(1);
#pragma unroll
    for (int mf = 0; mf < 4; mf++)
#pragma unroll
      for (int nf = 0; nf < 2; nf++) {
        acc[mf][nf + 2] = __builtin_amdgcn_mfma_f32_16x16x32_f16(af[mf][0], bf[nf][0], acc[mf][nf + 2], 0, 0, 0);
        acc[mf][nf + 2] = __builtin_amdgcn_mfma_f32_16x16x32_f16(af[mf][1], bf[nf][1], acc[mf][nf + 2], 0, 0, 0);
      }
    __builtin_amdgcn_s_setprio(0);
    __builtin_amdgcn_s_barrier();
    // ---------- phase 2: (m 4-7, n 2-3), bf kept ----------
    if (pre) STG_B23(nB, t + 1);
    if (pre) asm volatile("s_waitcnt vmcnt(6)" ::: "memory");
    else     asm volatile("s_waitcnt vmcnt(0)" ::: "memory");
    __builtin_amdgcn_s_barrier();
    __builtin_amdgcn_sched_barrier(0);
#pragma unroll
    for (int mf = 0; mf < 4; mf++) {
      af[mf][0] = *(const f16x8*)&cA[aRow + (mf + 4) * 1024 + c0];
      af[mf][1] = *(const f16x8*)&cA[aRow + (mf + 4) * 1024 + c1];
    }
    asm volatile("s_waitcnt lgkmcnt(0)" ::: "memory");
    __builtin_amdgcn_sched_barrier(0);
    __builtin_amdgcn_s_setprio(1);
#pragma unroll
    for (int mf = 0; mf < 4; mf++)
#pragma unroll
      for (int nf = 0; nf < 2; nf++) {
        acc[mf + 4][nf + 2] = __builtin_amdgcn_mfma_f32_16x16x32_f16(af[mf][0], bf[nf][0], acc[mf + 4][nf + 2], 0, 0, 0);
        acc[mf + 4][nf + 2] = __builtin_amdgcn_mfma_f32_16x16x32_f16(af[mf][1], bf[nf][1], acc[mf + 4][nf + 2], 0, 0, 0);
      }
    __builtin_amdgcn_s_setprio(0);
    __builtin_amdgcn_s_barrier();
    // ---------- phase 3: (m 4-7, n 0-1), af kept, bf re-read (old data) ----------
    if (pre) STG_A23(nA, t + 1);
    __builtin_amdgcn_s_barrier();
    __builtin_amdgcn_sched_barrier(0);
#pragma unroll
    for (int nf = 0; nf < 2; nf++) {
      bf[nf][0] = *(const f16x8*)&cB[bRow + nf * 1024 + c0];
      bf[nf][1] = *(const f16x8*)&cB[bRow + nf * 1024 + c1];
    }
    asm volatile("s_waitcnt lgkmcnt(0)" ::: "memory");
    __builtin_amdgcn_sched_barrier(0);
    __builtin_amdgcn_s_setprio(1);
#pragma unroll
    for (int mf = 0; mf < 4; mf++)
#pragma unroll
      for (int nf = 0; nf < 2; nf++) {
        acc[mf + 4][nf] = __builtin_amdgcn_mfma_f32_16x16x32_f16(af[mf][0], bf[nf][0], acc[mf + 4][nf], 0, 0, 0);
        acc[mf + 4][nf] = __builtin_amdgcn_mfma_f32_16x16x32_f16(af[mf][1], bf[nf][1], acc[mf + 4][nf], 0, 0, 0);
      }
    __builtin_amdgcn_s_setprio(0);
    __builtin_amdgcn_s_barrier();
    // swap double buffers
    { f16* tt = cA; cA = nA; nA = tt; }
    { f16* tt = cB; cB = nB; nB = tt; }
  }
#undef STG_A01
#undef STG_A23
#undef STG_B01
#undef STG_B23

#pragma unroll
  for (int mf = 0; mf < 8; mf++) {
    int row = mBase + wm + mf * 16 + quad * 4;
#pragma unroll
    for (int nf = 0; nf < 4; nf++) {
      int col = nBase + wn + nf * 16 + l16;
      OutT* Cp = C + (size_t)row * N + col;
#pragma unroll
      for (int r = 0; r < 4; r++) Cp[(size_t)r * N] = (OutT)acc[mf][nf][r];
    }
  }
}

// ---------------- sliding-tile flash attention (swapped-operand) ----------
// grid (T=32 tiles, NH=32, B=2), 256 threads = 4 waves, 32 q-rows each.
// Swapped QK^T: S^T = mfma(K-frag, Q-frag) -> lane l16 owns ONE q column:
// row-max/sum are 15 in-lane fmax + 2 shfl_xor (vs 32 shfls before); P is
// written packed (f16x4, b64) to sPt[q][k]; PV is O^T = mfma(V^T, P^T).
// Q is staged through sPt (freed before first P write) -> LDS 36.9 KB ->
// 4 blocks/CU (16 waves) vs 2 before. sVt keeps col ^= (d&56) XOR swizzle;
// V staged in token pairs (f16x2 writes, 2-way-free).
__global__ __launch_bounds__(256) void attn_kernel(const f16* __restrict__ Q,
                                                   const f16* __restrict__ Kg,
                                                   const f16* __restrict__ V,
                                                   f16* __restrict__ O) {
  __shared__ f16 sK[64 * 72];
  __shared__ f16 sVt[64 * 72];    // V transposed: [d][k ^ (d&56)]
  __shared__ f16 sPt[128 * 72];   // P[q][k] packed; also Q staging buffer

  int t = blockIdx.x, h = blockIdx.y, b = blockIdx.z;
  int nth_i = t >> 2, ntw_i = t & 3;    // Ht=8, Wt=4
  int tid = threadIdx.x;
  int lane = tid & 63, wave = tid >> 6;
  int quad = lane >> 4, l16 = lane & 15;
  const size_t bstride = (size_t)N_SEQ * K_HID;
  const f16* Qb = Q + (size_t)b * bstride + h * 64;
  const f16* Kb = Kg + (size_t)b * bstride + h * 64;
  const f16* Vb = V + (size_t)b * bstride + h * 64;

  const float SC2 = 0.18033688f;   // (1/sqrt(64)) * log2(e)

  // stage Q tile [128 x 64] via sPt: row qr -> token s
  for (int i = tid; i < 1024; i += 256) {
    int qr = i >> 3, dc = (i & 7) * 8;
    int s = (nth_i * 8 + (qr >> 4)) * 64 + ntw_i * 16 + (qr & 15);
    *(float4*)&sPt[qr * 72 + dc] = *(const float4*)&Qb[(size_t)s * K_HID + dc];
  }
  __syncthreads();

  f16x8 qf[2][2];   // [q-subtile][d-half]; identical layout as A or B operand
#pragma unroll
  for (int qs = 0; qs < 2; qs++)
#pragma unroll
    for (int kk = 0; kk < 2; kk++)
      qf[qs][kk] = *(const f16x8*)&sPt[(wave * 32 + qs * 16 + l16) * 72 + kk * 32 + quad * 8];
  // qf reads drain at chunk-0's post-stage __syncthreads before sPt reuse.

  f32x4 oacc[2][4];   // O^T: [qs][dt], col=l16=q, row=quad*4+r=d within dt
#pragma unroll
  for (int qs = 0; qs < 2; qs++)
#pragma unroll
    for (int dt = 0; dt < 4; dt++) oacc[qs][dt] = (f32x4){0.f, 0.f, 0.f, 0.f};
  float mrow[2] = {-1e30f, -1e30f};
  float lrow[2] = {0.f, 0.f};   // quad-partial rowsum; reduced at finalize

  int cr = min(max(nth_i, 1), 7);   // clamped window center (tile units)
  int cc = min(max(ntw_i, 1), 3);

  for (int c = 0; c < 8; c++) {
    int kt = c >> 1, half = c & 1;
    int ti = cr - 1 + (kt >> 1), tj = cc - 1 + (kt & 1);
    // stage K chunk [64 x 64] (row-major, +72 pad)
    for (int i = tid; i < 512; i += 256) {
      int kl = i >> 3, dc = (i & 7) * 8;
      int kr = half * 64 + kl;
      int s = (ti * 8 + (kr >> 4)) * 64 + tj * 16 + (kr & 15);
      *(float4*)&sK[kl * 72 + dc] = *(const float4*)&Kb[(size_t)s * K_HID + dc];
    }
    // stage swizzled V^T in token PAIRS: thread -> (pair, d-chunk), 8 f16x2
    {
      int pr = tid >> 3, dc = (tid & 7) * 8;
      int k0 = pr * 2;
      int kr0 = half * 64 + k0, kr1 = kr0 + 1;
      int s0 = (ti * 8 + (kr0 >> 4)) * 64 + tj * 16 + (kr0 & 15);
      int s1 = (ti * 8 + (kr1 >> 4)) * 64 + tj * 16 + (kr1 & 15);
      f16x8 v0 = *(const f16x8*)&Vb[(size_t)s0 * K_HID + dc];
      f16x8 v1 = *(const f16x8*)&Vb[(size_t)s1 * K_HID + dc];
      int swc = k0 ^ dc;   // dc == (d & 56) for rows dc..dc+7; k0 even
#pragma unroll
      for (int j = 0; j < 8; j++) {
        f16x2 pv; pv[0] = v0[j]; pv[1] = v1[j];
        *(f16x2*)&sVt[(dc + j) * 72 + swc] = pv;
      }
    }
    __syncthreads();

    // S^T = K Q^T: sacc[qs][ks] col=l16=q, row=quad*4+r=k within ks block
    f32x4 sacc[2][4];
#pragma unroll
    for (int qs = 0; qs < 2; qs++)
#pragma unroll
      for (int ks = 0; ks < 4; ks++) sacc[qs][ks] = (f32x4){0.f, 0.f, 0.f, 0.f};
#pragma unroll
    for (int ks = 0; ks < 4; ks++) {
      f16x8 kf0 = *(const f16x8*)&sK[(ks * 16 + l16) * 72 + quad * 8];
      f16x8 kf1 = *(const f16x8*)&sK[(ks * 16 + l16) * 72 + 32 + quad * 8];
#pragma unroll
      for (int qs = 0; qs < 2; qs++) {
        sacc[qs][ks] = __builtin_amdgcn_mfma_f32_16x16x32_f16(kf0, qf[qs][0], sacc[qs][ks], 0, 0, 0);
        sacc[qs][ks] = __builtin_amdgcn_mfma_f32_16x16x32_f16(kf1, qf[qs][1], sacc[qs][ks], 0, 0, 0);
      }
    }

    // online softmax: lane owns q = l16; in-lane max over 16 + 2 cross-quad
#pragma unroll
    for (int qs = 0; qs < 2; qs++) {
      float mx = sacc[qs][0][0];
#pragma unroll
      for (int ks = 0; ks < 4; ks++)
#pragma unroll
        for (int r = 0; r < 4; r++) mx = fmaxf(mx, sacc[qs][ks][r]);
      mx = fmaxf(mx, __shfl_xor(mx, 16, 64));
      mx = fmaxf(mx, __shfl_xor(mx, 32, 64));
      mx *= SC2;
      float mold = mrow[qs];
      float mnew = fmaxf(mold, mx);
      mrow[qs] = mnew;
      float alpha = exp2f(mold - mnew);   // mold=-1e30 -> 0
      lrow[qs] *= alpha;
#pragma unroll
      for (int dt = 0; dt < 4; dt++)
#pragma unroll
        for (int r = 0; r < 4; r++) oacc[qs][dt][r] *= alpha;
      float ls = 0.f;
      int qrow = (wave * 32 + qs * 16 + l16) * 72;
#pragma unroll
      for (int ks = 0; ks < 4; ks++) {
        f16x4 pk;
#pragma unroll
        for (int r = 0; r < 4; r++) {
          float p = exp2f(sacc[qs][ks][r] * SC2 - mnew);
          ls += p;
          pk[r] = (f16)p;
        }
        *(f16x4*)&sPt[qrow + ks * 16 + quad * 4] = pk;   // P[q][k] b64 write
      }
      lrow[qs] += ls;
    }
    __syncthreads();

    // O^T += V^T P^T: A = V^T frag (rows d), B = P^T frag (cols q)
#pragma unroll
    for (int kk = 0; kk < 2; kk++) {
      f16x8 pf[2];
#pragma unroll
      for (int qs = 0; qs < 2; qs++)
        pf[qs] = *(const f16x8*)&sPt[(wave * 32 + qs * 16 + l16) * 72 + kk * 32 + quad * 8];
#pragma unroll
      for (int dt = 0; dt < 4; dt++) {
        int d = dt * 16 + l16;
        f16x8 vf = *(const f16x8*)&sVt[d * 72 + ((kk * 32 + quad * 8) ^ (d & 56))];
#pragma unroll
        for (int qs = 0; qs < 2; qs++)
          oacc[qs][dt] = __builtin_amdgcn_mfma_f32_16x16x32_f16(vf, pf[qs], oacc[qs][dt], 0, 0, 0);
      }
    }
    __syncthreads();
  }

  // finalize: cross-quad l reduce (2 shfl), divide, packed b64 stores
  f16* Ob = O + (size_t)b * bstride + h * 64;
#pragma unroll
  for (int qs = 0; qs < 2; qs++) {
    float l = lrow[qs];
    l += __shfl_xor(l, 16, 64);
    l += __shfl_xor(l, 32, 64);
    float inv = 1.0f / l;
    int q = wave * 32 + qs * 16 + l16;
    int s = (nth_i * 8 + (q >> 4)) * 64 + ntw_i * 16 + (q & 15);
#pragma unroll
    for (int dt = 0; dt < 4; dt++) {
      f16x4 ok;
#pragma unroll
      for (int r = 0; r < 4; r++) ok[r] = (f16)(oacc[qs][dt][r] * inv);
      *(f16x4*)&Ob[(size_t)s * K_HID + dt * 16 + quad * 4] = ok;
    }
  }
}

extern "C" void kernel_launch(void* const* d_in, const int* in_sizes, int n_in,
                              void* d_out, int out_size, void* d_ws, size_t ws_size,
                              hipStream_t stream) {
  const float* hs = (const float*)d_in[0];
  const float* Wq = (const float*)d_in[1];
  const float* Wk = (const float*)d_in[2];
  const float* Wv = (const float*)d_in[3];
  const float* Wo = (const float*)d_in[4];
  float* out = (float*)d_out;

  char* ws = (char*)d_ws;
  const size_t WELEM = (size_t)K_HID * K_HID;      // 4,194,304
  const size_t XELEM = (size_t)M_ROWS * K_HID;     // 16,777,216
  f16* WT = (f16*)ws;  ws += 4 * WELEM * sizeof(f16);  // WqT,WkT,WvT,WoT
  f16* Xh = (f16*)ws;  ws += XELEM * sizeof(f16);
  f16* Qb = (f16*)ws;  ws += XELEM * sizeof(f16);      // Q,K,V contiguous
  f16* Kb = (f16*)ws;  ws += XELEM * sizeof(f16);
  f16* Vb = (f16*)ws;  ws += XELEM * sizeof(f16);
  f16* Ob = (f16*)ws;  ws += XELEM * sizeof(f16);

  cvt_f32_to_f16<<<(int)(XELEM / (256 * 8)), 256, 0, stream>>>(hs, Xh, (int)XELEM);
  transpose_cvt<<<dim3(64, 64, 4), 256, 0, stream>>>(Wq, Wk, Wv, Wo, WT);
  gemm_bt<f16><<<dim3(8, 32, 3), 512, 0, stream>>>(Xh, WT, Qb, M_ROWS, K_HID, K_HID,
                                                   WELEM, XELEM);
  attn_kernel<<<dim3(32, 32, 2), 256, 0, stream>>>(Qb, Kb, Vb, Ob);
  gemm_bt<float><<<dim3(8, 32, 1), 512, 0, stream>>>(Ob, WT + 3 * WELEM, out,
                                                     M_ROWS, K_HID, K_HID, 0, 0);
}